// Round 4
// baseline (115.239 us; speedup 1.0000x reference)
//
#include <hip/hip_runtime.h>

#define KW 7
#define TW 128           // tile width (output cols per block)
#define STH 32           // sub-tile height (output rows per step)
#define NSTEP 4          // sub-tiles per block -> 128-row region
#define LH 38            // STH + 6 halo rows
#define LWIDE 136        // TW + 8 halo cols (34 float4 chunks, 16B-aligned)
#define NCH 34           // float4 chunks per LDS row
#define CHT (LH * NCH)   // 1292 chunks per sub-tile
#define NIT 6            // ceil(CHT / 256)

__global__ __launch_bounds__(256)
void conv7x7_kernel(const float* __restrict__ x, const float* __restrict__ w,
                    float* __restrict__ out) {
    __shared__ float tile[2][LH * LWIDE];   // 2 x 20672 B -> 3 blocks/CU

    const int H = 512, W = 512;
    const int bi  = blockIdx.x;             // 2048 blocks: n(7) | ry(2) | rx(2)
    const int n   = bi >> 4;
    const int ry0 = ((bi >> 2) & 3) * (NSTEP * STH);
    const int tx0 = (bi & 3) * TW;

    const float* xn = x + (size_t)n * H * W;
    float*       on = out + (size_t)n * H * W;

    float wr[49];
#pragma unroll
    for (int i = 0; i < 49; ++i) wr[i] = w[i];

    const int t = threadIdx.x;

    // k-invariant staging descriptors
    int  s_tr[NIT], s_eoff[NIT], s_loff[NIT];
    bool s_ok[NIT];
#pragma unroll
    for (int it = 0; it < NIT; ++it) {
        const int idx = t + 256 * it;
        const int tr  = idx / NCH;
        const int ci  = idx - tr * NCH;
        const int gc  = tx0 - 4 + 4 * ci;   // full-or-zero chunks at x borders
        s_tr[it]   = tr;
        s_eoff[it] = tr * W + gc;
        s_loff[it] = tr * LWIDE + 4 * ci;
        s_ok[it]   = (idx < CHT) && (gc >= 0) && (gc <= W - 4);
    }

    const int cg = t & 31;
    const int rg = t >> 5;
    const int c0 = 4 * cg;
    const int r0 = 4 * rg;

    float4 sreg[NIT];

#define STAGE_ISSUE(kk_)                                                        \
    {                                                                           \
        const int grb = ry0 + STH * (kk_) - 3;                                  \
        _Pragma("unroll")                                                       \
        for (int it = 0; it < NIT; ++it) {                                      \
            const int gr = grb + s_tr[it];                                      \
            float4 v = make_float4(0.f, 0.f, 0.f, 0.f);                         \
            if (s_ok[it] && gr >= 0 && gr < H)                                  \
                v = *reinterpret_cast<const float4*>(&xn[grb * W + s_eoff[it]]);\
            sreg[it] = v;                                                       \
        }                                                                       \
    }

#define STAGE_WRITE(buf_)                                                       \
    {                                                                           \
        _Pragma("unroll")                                                       \
        for (int it = 0; it < NIT; ++it) {                                      \
            if (t + 256 * it < CHT)                                             \
                *reinterpret_cast<float4*>(&tile[buf_][s_loff[it]]) = sreg[it]; \
        }                                                                       \
    }

    // prologue: stage sub-tile 0
    STAGE_ISSUE(0)
    STAGE_WRITE(0)
    __syncthreads();

    for (int k = 0; k < NSTEP; ++k) {
        const int buf = k & 1;

        if (k + 1 < NSTEP) STAGE_ISSUE(k + 1)   // loads in flight during compute

        // ---- compute 4x4 micro-tile from tile[buf] ----
        float acc[4][4];
#pragma unroll
        for (int i = 0; i < 4; ++i)
#pragma unroll
            for (int j = 0; j < 4; ++j) acc[i][j] = 0.f;

        const float* lp = &tile[buf][r0 * LWIDE + c0];
#pragma unroll
        for (int s = 0; s < 10; ++s) {
            float v[12];
#pragma unroll
            for (int p = 0; p < 3; ++p) {
                const float4 tmp = *reinterpret_cast<const float4*>(lp + 4 * p);
                v[4 * p]     = tmp.x;
                v[4 * p + 1] = tmp.y;
                v[4 * p + 2] = tmp.z;
                v[4 * p + 3] = tmp.w;
            }
            lp += LWIDE;
#pragma unroll
            for (int i = 0; i < 4; ++i) {
                const int a = s - i;            // weight row
                if (a >= 0 && a < KW) {
#pragma unroll
                    for (int j = 0; j < 4; ++j)
#pragma unroll
                        for (int dj = 0; dj < KW; ++dj)
                            acc[i][j] += v[1 + j + dj] * wr[a * KW + dj];
                }
            }
        }

        if (k + 1 < NSTEP) STAGE_WRITE((k + 1) & 1)

        // ---- store 4 rows x float4 ----
        const int gro = ry0 + STH * k + r0;
#pragma unroll
        for (int i = 0; i < 4; ++i) {
            *reinterpret_cast<float4*>(&on[(size_t)(gro + i) * W + tx0 + c0]) =
                make_float4(acc[i][0], acc[i][1], acc[i][2], acc[i][3]);
        }

        __syncthreads();
    }

#undef STAGE_ISSUE
#undef STAGE_WRITE
}

extern "C" void kernel_launch(void* const* d_in, const int* in_sizes, int n_in,
                              void* d_out, int out_size, void* d_ws, size_t ws_size,
                              hipStream_t stream) {
    const float* x = (const float*)d_in[0];
    const float* w = (const float*)d_in[1];
    float* out = (float*)d_out;

    const int nblocks = 128 * 4 * 4;   // 2048 persistent region blocks
    conv7x7_kernel<<<nblocks, 256, 0, stream>>>(x, w, out);
}

// Round 5
// 74.295 us; speedup vs baseline: 1.5511x; 1.5511x over previous
//
#include <hip/hip_runtime.h>

#define KW 7
#define S 16               // output rows per band
#define NBANDS 32          // 512 / S

// Thread t -> output cols 4t..4t+3 of one 16-row band. No LDS.
// Sliding register window: acc[j] = partial sums for output row (o_next + j).

__global__ __launch_bounds__(128)
void conv7x7_kernel(const float* __restrict__ x, const float* __restrict__ w,
                    float* __restrict__ out) {
    const int W = 512, H = 512;
    const int bi   = blockIdx.x;
    const int n    = bi >> 5;
    const int band = bi & 31;
    const int y0   = band * S;

    const float* xn = x + (size_t)n * (W * H);
    float*       on = out + (size_t)n * (W * H);

    // Uniform weight reads -> scalar loads (SGPRs)
    float wr[49];
#pragma unroll
    for (int i = 0; i < 49; ++i) wr[i] = w[i];

    const int  t   = threadIdx.x;
    const int  cb  = t * 4;
    const bool ok0 = (cb >= 4);        // left halo chunk in-bounds
    const bool ok2 = (cb <= W - 8);    // right halo chunk in-bounds

    float acc[7][4];
#pragma unroll
    for (int j = 0; j < 7; ++j)
#pragma unroll
        for (int c = 0; c < 4; ++c) acc[j][c] = 0.f;

    float va[12], vb[12];

    // Load input row r (block-uniform r) into a 12-float window: cols cb-4 .. cb+7
#define LOADROW(vbuf, r_)                                                      \
    {                                                                          \
        const int r__ = (r_);                                                  \
        if (r__ >= 0 && r__ < H) {                                             \
            const float* rp = xn + r__ * W + cb;                               \
            const float4 A = ok0 ? *reinterpret_cast<const float4*>(rp - 4)    \
                                 : make_float4(0.f, 0.f, 0.f, 0.f);            \
            const float4 B = *reinterpret_cast<const float4*>(rp);             \
            const float4 C = ok2 ? *reinterpret_cast<const float4*>(rp + 4)    \
                                 : make_float4(0.f, 0.f, 0.f, 0.f);            \
            vbuf[0]=A.x; vbuf[1]=A.y; vbuf[2]=A.z;  vbuf[3]=A.w;               \
            vbuf[4]=B.x; vbuf[5]=B.y; vbuf[6]=B.z;  vbuf[7]=B.w;               \
            vbuf[8]=C.x; vbuf[9]=C.y; vbuf[10]=C.z; vbuf[11]=C.w;              \
        } else {                                                               \
            _Pragma("unroll")                                                  \
            for (int q = 0; q < 12; ++q) vbuf[q] = 0.f;                        \
        }                                                                      \
    }

    // acc[j_] += window * weight-row k_   (28 FMAs)
#define ACCUM(vbuf, j_, k_)                                                    \
    {                                                                          \
        _Pragma("unroll")                                                      \
        for (int c = 0; c < 4; ++c)                                            \
            _Pragma("unroll")                                                  \
            for (int d = 0; d < KW; ++d)                                       \
                acc[j_][c] += vbuf[1 + c + d] * wr[(k_) * KW + d];             \
    }

    // Complete output row o_ from vbuf (weight rows 6-j), store, shift ring
#define MAIN(vbuf, o_)                                                         \
    {                                                                          \
        ACCUM(vbuf, 0, 6) ACCUM(vbuf, 1, 5) ACCUM(vbuf, 2, 4)                  \
        ACCUM(vbuf, 3, 3) ACCUM(vbuf, 4, 2) ACCUM(vbuf, 5, 1)                  \
        ACCUM(vbuf, 6, 0)                                                      \
        *reinterpret_cast<float4*>(on + (o_) * W + cb) =                       \
            make_float4(acc[0][0], acc[0][1], acc[0][2], acc[0][3]);           \
        _Pragma("unroll")                                                      \
        for (int j = 0; j < 6; ++j)                                            \
            _Pragma("unroll")                                                  \
            for (int c = 0; c < 4; ++c) acc[j][c] = acc[j + 1][c];             \
        _Pragma("unroll")                                                      \
        for (int c = 0; c < 4; ++c) acc[6][c] = 0.f;                           \
    }

    // ---- prologue: rows y0-3 .. y0+2 (i = 0..5), pipelined A/B ----
    LOADROW(va, y0 - 3)                                   // i=0
    LOADROW(vb, y0 - 2)                                   // i=1
    ACCUM(va, 0, 0)                                       // P(0)
    LOADROW(va, y0 - 1)                                   // i=2
    ACCUM(vb, 0, 1) ACCUM(vb, 1, 0)                       // P(1)
    LOADROW(vb, y0 + 0)                                   // i=3
    ACCUM(va, 0, 2) ACCUM(va, 1, 1) ACCUM(va, 2, 0)       // P(2)
    LOADROW(va, y0 + 1)                                   // i=4
    ACCUM(vb, 0, 3) ACCUM(vb, 1, 2) ACCUM(vb, 2, 1)
    ACCUM(vb, 3, 0)                                       // P(3)
    LOADROW(vb, y0 + 2)                                   // i=5
    ACCUM(va, 0, 4) ACCUM(va, 1, 3) ACCUM(va, 2, 2)
    ACCUM(va, 3, 1) ACCUM(va, 4, 0)                       // P(4)
    LOADROW(va, y0 + 3)                                   // i=6 (first main row)
    ACCUM(vb, 0, 5) ACCUM(vb, 1, 4) ACCUM(vb, 2, 3)
    ACCUM(vb, 3, 2) ACCUM(vb, 4, 1) ACCUM(vb, 5, 0)       // P(5)

    // ---- main: 16 steps, 2-stage register pipeline ----
    for (int s = 0; s < S; s += 2) {
        LOADROW(vb, y0 + 4 + s)          // row for step s+1
        MAIN(va, y0 + s)                 // hides vb load under 196 FMAs
        if (s < S - 2) LOADROW(va, y0 + 5 + s)   // row for step s+2
        MAIN(vb, y0 + s + 1)
    }

#undef LOADROW
#undef ACCUM
#undef MAIN
}

extern "C" void kernel_launch(void* const* d_in, const int* in_sizes, int n_in,
                              void* d_out, int out_size, void* d_ws, size_t ws_size,
                              hipStream_t stream) {
    const float* x = (const float*)d_in[0];
    const float* w = (const float*)d_in[1];
    float* out = (float*)d_out;

    const int nblocks = 128 * NBANDS;   // 4096 blocks x 128 threads
    conv7x7_kernel<<<nblocks, 128, 0, stream>>>(x, w, out);
}